// Round 32
// baseline (163.012 us; speedup 1.0000x reference)
//
#include <hip/hip_runtime.h>
#include <hip/hip_bf16.h>

// SNN: B=2048, NI=1024, NH=2048, NO=10, T=128, BETA=0.95, THR=1.0
// r32 = exact revert to r29 (session-best verified: 162.92us, absmax
// 1.203125). r30/r31's in-asm store loop produced bit-identical wrong
// output across two different hazard orderings -> store path broken in a
// way not debuggable without disasm; reverted per rigor discipline.
// Pipeline: convert_hl (K'=3072 segments) -> gemm_cur1 (bf16 MFMA,
// hh+hl+lh) -> spikegen (single-block asm LIF, C++ store) -> snn_out.

#define B_   2048
#define NI_  1024
#define NH_  2048
#define NO_  10
#define T_   128
#define KP   3072   // concatenated K'

typedef __attribute__((ext_vector_type(8))) short short8;
typedef __attribute__((ext_vector_type(4))) float f32x4;
typedef __attribute__((ext_vector_type(4))) unsigned int u32x4;

__device__ __forceinline__ unsigned int bf16_rne(float f) {
  unsigned int u = __float_as_uint(f);
  return (u + 0x7FFFu + ((u >> 16) & 1u)) >> 16;
}

// ---------------- Kernel 0: convert x,w1 -> bf16 segment rows (K'=3072) -----
// xc row  = [xh(0..1023) | xh | xl];  w1c row = [wh | wl | wh].
__global__ __launch_bounds__(256) void convert_hl(
    const float* __restrict__ x, const float* __restrict__ w1,
    unsigned short* __restrict__ xc, unsigned short* __restrict__ w1c) {
  const int gidx = blockIdx.x * 256 + threadIdx.x;   // 0..2^20-1
  const int mat = gidx >> 19;
  const int loc = gidx & 524287;
  const int row = loc >> 8;
  const int kq = loc & 255;                          // float4 index in row

  const float* src = (mat ? w1 : x) + (size_t)row * NI_ + kq * 4;
  unsigned short* dst = (mat ? w1c : xc) + (size_t)row * KP + kq * 4;
  const int hi2_off = mat ? 2048 : 1024;  // second hi segment
  const int lo_off  = mat ? 1024 : 2048;  // lo segment

  const float4 v = *reinterpret_cast<const float4*>(src);
  const float f[4] = {v.x, v.y, v.z, v.w};
  unsigned h[4], l[4];
#pragma unroll
  for (int c = 0; c < 4; ++c) {
    h[c] = bf16_rne(f[c]);
    l[c] = bf16_rne(f[c] - __uint_as_float(h[c] << 16));
  }
  const uint2 hw = uint2{h[0] | (h[1] << 16), h[2] | (h[3] << 16)};
  const uint2 lw = uint2{l[0] | (l[1] << 16), l[2] | (l[3] << 16)};
  *reinterpret_cast<uint2*>(dst) = hw;
  *reinterpret_cast<uint2*>(dst + hi2_off) = hw;
  *reinterpret_cast<uint2*>(dst + lo_off) = lw;
}

// ---------------- Kernel 1: cur1 = xc @ w1c^T + b1 (bf16 GEMM, K'=3072) -----
#define RS 144
#define GA_OFF 0
#define GB_OFF (64 * RS)             // 9216
#define G2_SMEM (GB_OFF + 128 * RS)  // 27648

__global__ __launch_bounds__(512, 2) void gemm_cur1(
    const unsigned short* __restrict__ xc,
    const unsigned short* __restrict__ w1c,
    const float* __restrict__ b1, float* __restrict__ cur1) {
  __shared__ __align__(16) char smem[G2_SMEM];
  const int tid = threadIdx.x;
  const int lane = tid & 63;
  const int wv = tid >> 6;
  const int wm = wv >> 2;
  const int wn = wv & 3;
  const int n15 = lane & 15;
  const int g = lane >> 4;
  const int brow = blockIdx.y * 64;
  const int bcol = blockIdx.x * 128;

  const int s_row = tid >> 3;
  const int s_o16 = tid & 7;

  f32x4 acc[2][2];
#pragma unroll
  for (int tm = 0; tm < 2; ++tm)
#pragma unroll
    for (int tn = 0; tn < 2; ++tn) acc[tm][tn] = f32x4{0, 0, 0, 0};

  for (int kt = 0; kt < KP; kt += 64) {
    {
      const uint4 v = *reinterpret_cast<const uint4*>(
          xc + (size_t)(brow + s_row) * KP + kt + s_o16 * 8);
      *reinterpret_cast<uint4*>(smem + GA_OFF + s_row * RS + s_o16 * 16) = v;
    }
#pragma unroll
    for (int p = 0; p < 2; ++p) {
      const int s = tid + p * 512;
      const int row = s >> 3, o16 = s & 7;
      const uint4 v = *reinterpret_cast<const uint4*>(
          w1c + (size_t)(bcol + row) * KP + kt + o16 * 8);
      *reinterpret_cast<uint4*>(smem + GB_OFF + row * RS + o16 * 16) = v;
    }
    __syncthreads();

#pragma unroll
    for (int kk = 0; kk < 2; ++kk) {
      short8 af[2], bf[2];
#pragma unroll
      for (int tm = 0; tm < 2; ++tm)
        af[tm] = *reinterpret_cast<const short8*>(
            smem + GA_OFF + (wm * 32 + tm * 16 + n15) * RS + kk * 64 + g * 16);
#pragma unroll
      for (int tn = 0; tn < 2; ++tn)
        bf[tn] = *reinterpret_cast<const short8*>(
            smem + GB_OFF + (wn * 32 + tn * 16 + n15) * RS + kk * 64 + g * 16);
#pragma unroll
      for (int tm = 0; tm < 2; ++tm)
#pragma unroll
        for (int tn = 0; tn < 2; ++tn)
          acc[tm][tn] = __builtin_amdgcn_mfma_f32_16x16x32_bf16(
              af[tm], bf[tn], acc[tm][tn], 0, 0, 0);
    }
    __syncthreads();
  }

#pragma unroll
  for (int tn = 0; tn < 2; ++tn) {
    const int col = bcol + wn * 32 + tn * 16 + n15;
    const float bias = b1[col];
#pragma unroll
    for (int tm = 0; tm < 2; ++tm) {
      const int rowb = brow + wm * 32 + tm * 16 + g * 4;
#pragma unroll
      for (int r = 0; r < 4; ++r)
        cur1[(size_t)(rowb + r) * NH_ + col] = acc[tm][tn][r] + bias;
    }
  }
}

// ---------------- Kernel A: spikegen — inline-asm LIF v3 (single block) -----
// 512 threads = 8 waves = 2 batches (bq=w>>2, qf=w&3); 8 neurons/lane.
// Byte b = qf*64+lane of the (b,t) 256-byte row covers neurons 8b..8b+7.
// Per neuron-step: fma, cmp, cndmask-s, sub-cc, addc = 5 inst; one block.
__global__ __launch_bounds__(512) void spikegen(
    const float* __restrict__ cur1, unsigned char* __restrict__ bits8) {
  const int lane = threadIdx.x & 63;
  const int w = threadIdx.x >> 6;
  const int bq = w >> 2;
  const int qf = w & 3;
  const int bb = blockIdx.x * 2 + bq;

  float m0, m1, m2, m3, m4, m5, m6, m7;
  float v0, v1, v2, v3, v4, v5, v6, v7;   // c1
  float c0, c1_, c2, c3, c4, c5, c6, c7;  // cc carry
  {
    const float* base = cur1 + (size_t)bb * NH_ + qf * 512 + lane * 8;
    const float4 a = *reinterpret_cast<const float4*>(base);
    const float4 b = *reinterpret_cast<const float4*>(base + 4);
    v0 = a.x; v1 = a.y; v2 = a.z; v3 = a.w;
    v4 = b.x; v5 = b.y; v6 = b.z; v7 = b.w;
    c0 = v0; c1_ = v1; c2 = v2; c3 = v3;
    c4 = v4; c5 = v5; c6 = v6; c7 = v7;
    m0 = m1 = m2 = m3 = m4 = m5 = m6 = m7 = 0.0f;
  }

  float fone = 1.0f;
  unsigned char* dst = bits8 + (size_t)bb * T_ * 256 + qf * 64 + lane;

  for (int t = 0; t < T_; ++t) {
    unsigned W = 0;
    float st;
    asm volatile(
        "v_fma_f32 %[m7], %[k], %[m7], %[c7]\n\t"
        "v_cmp_lt_f32 vcc, 1.0, %[m7]\n\t"
        "v_cndmask_b32 %[s], 0, %[one], vcc\n\t"
        "v_sub_f32 %[c7], %[v7], %[s]\n\t"
        "v_addc_co_u32 %[wr], vcc, %[wr], %[wr], vcc\n\t"
        "v_fma_f32 %[m6], %[k], %[m6], %[c6]\n\t"
        "v_cmp_lt_f32 vcc, 1.0, %[m6]\n\t"
        "v_cndmask_b32 %[s], 0, %[one], vcc\n\t"
        "v_sub_f32 %[c6], %[v6], %[s]\n\t"
        "v_addc_co_u32 %[wr], vcc, %[wr], %[wr], vcc\n\t"
        "v_fma_f32 %[m5], %[k], %[m5], %[c5]\n\t"
        "v_cmp_lt_f32 vcc, 1.0, %[m5]\n\t"
        "v_cndmask_b32 %[s], 0, %[one], vcc\n\t"
        "v_sub_f32 %[c5], %[v5], %[s]\n\t"
        "v_addc_co_u32 %[wr], vcc, %[wr], %[wr], vcc\n\t"
        "v_fma_f32 %[m4], %[k], %[m4], %[c4]\n\t"
        "v_cmp_lt_f32 vcc, 1.0, %[m4]\n\t"
        "v_cndmask_b32 %[s], 0, %[one], vcc\n\t"
        "v_sub_f32 %[c4], %[v4], %[s]\n\t"
        "v_addc_co_u32 %[wr], vcc, %[wr], %[wr], vcc\n\t"
        "v_fma_f32 %[m3], %[k], %[m3], %[c3]\n\t"
        "v_cmp_lt_f32 vcc, 1.0, %[m3]\n\t"
        "v_cndmask_b32 %[s], 0, %[one], vcc\n\t"
        "v_sub_f32 %[c3], %[v3], %[s]\n\t"
        "v_addc_co_u32 %[wr], vcc, %[wr], %[wr], vcc\n\t"
        "v_fma_f32 %[m2], %[k], %[m2], %[c2]\n\t"
        "v_cmp_lt_f32 vcc, 1.0, %[m2]\n\t"
        "v_cndmask_b32 %[s], 0, %[one], vcc\n\t"
        "v_sub_f32 %[c2], %[v2], %[s]\n\t"
        "v_addc_co_u32 %[wr], vcc, %[wr], %[wr], vcc\n\t"
        "v_fma_f32 %[m1], %[k], %[m1], %[c1]\n\t"
        "v_cmp_lt_f32 vcc, 1.0, %[m1]\n\t"
        "v_cndmask_b32 %[s], 0, %[one], vcc\n\t"
        "v_sub_f32 %[c1], %[v1], %[s]\n\t"
        "v_addc_co_u32 %[wr], vcc, %[wr], %[wr], vcc\n\t"
        "v_fma_f32 %[m0], %[k], %[m0], %[c0]\n\t"
        "v_cmp_lt_f32 vcc, 1.0, %[m0]\n\t"
        "v_cndmask_b32 %[s], 0, %[one], vcc\n\t"
        "v_sub_f32 %[c0], %[v0], %[s]\n\t"
        "v_addc_co_u32 %[wr], vcc, %[wr], %[wr], vcc\n\t"
        : [wr] "+v"(W), [s] "=&v"(st),
          [m7] "+v"(m7), [m6] "+v"(m6), [m5] "+v"(m5), [m4] "+v"(m4),
          [m3] "+v"(m3), [m2] "+v"(m2), [m1] "+v"(m1), [m0] "+v"(m0),
          [c7] "+v"(c7), [c6] "+v"(c6), [c5] "+v"(c5), [c4] "+v"(c4),
          [c3] "+v"(c3), [c2] "+v"(c2), [c1] "+v"(c1_), [c0] "+v"(c0)
        : [k] "s"(0.95f), [one] "v"(fone),
          [v7] "v"(v7), [v6] "v"(v6), [v5] "v"(v5), [v4] "v"(v4),
          [v3] "v"(v3), [v2] "v"(v2), [v1] "v"(v1), [v0] "v"(v0)
        : "vcc");

    dst[t * 256] = (unsigned char)W;
  }
}

// ---------------- Kernel B: snn_out (r20 frozen) ----------------------------
#define SO_TC 16

__global__ __launch_bounds__(512, 2) void snn_out(
    const unsigned* __restrict__ bitsg, const float* __restrict__ w2,
    const float* __restrict__ b2, float* __restrict__ spk2_rec,
    float* __restrict__ mem2_rec) {
  __shared__ uint2 lut[16];
  __shared__ __align__(16) unsigned bitsl[64 * 68];
  __shared__ __align__(16) float comb[8 * 640];
  const int tid = threadIdx.x;
  const int lane = tid & 63;
  const int w = tid >> 6;
  const int bbase = blockIdx.x * 4;

  if (tid < 16) {
    lut[tid] = uint2{(tid & 1 ? 0x3F80u : 0u) | (tid & 2 ? 0x3F800000u : 0u),
                     (tid & 4 ? 0x3F80u : 0u) | (tid & 8 ? 0x3F800000u : 0u)};
  }

  u32x4 bhi[8];
  {
    const int o = lane & 15;
    const int koff = (lane >> 4) * 8;
#pragma unroll
    for (int kbl = 0; kbl < 8; ++kbl) {
      const int kb = w * 8 + kbl;
      unsigned int hw[4];
#pragma unroll
      for (int p = 0; p < 4; ++p) {
        unsigned int h0 = 0, h1 = 0;
        if (o < NO_) {
          const int k = kb * 32 + koff + p * 2;
          h0 = bf16_rne(w2[(size_t)o * NH_ + k]);
          h1 = bf16_rne(w2[(size_t)o * NH_ + k + 1]);
        }
        hw[p] = h0 | (h1 << 16);
      }
      bhi[kbl] = u32x4{hw[0], hw[1], hw[2], hw[3]};
    }
  }

  float mem2 = 0.0f, spk2 = 0.0f, b2v = 0.0f;
  float *srec = nullptr, *mrec = nullptr;
  if (w < 4 && lane < NO_) {
    b2v = b2[lane];
    srec = spk2_rec + (size_t)(bbase + w) * NO_ + lane;
    mrec = mem2_rec + (size_t)(bbase + w) * NO_ + lane;
  }

  const int n15 = lane & 15;
  const int g = lane >> 4;
  const unsigned char* bytes = reinterpret_cast<const unsigned char*>(bitsl);

  for (int ch = 0; ch < T_ / SO_TC; ++ch) {
#pragma unroll
    for (int j = 0; j < 2; ++j) {
      const int q = tid + j * 512;
      const int row = q >> 4;
      const int kq = q & 15;
      const int b = row >> 4, tl = row & 15;
      const uint4 v = *reinterpret_cast<const uint4*>(
          bitsg + ((size_t)(bbase + b) * T_ + ch * SO_TC + tl) * 64 + kq * 4);
      *reinterpret_cast<uint4*>(bitsl + row * 68 + kq * 4) = v;
    }
    __syncthreads();

#pragma unroll
    for (int b = 0; b < 4; ++b) {
      const int rbase = ((b * SO_TC + n15) * 68 + w * 8) * 4 + g;
      f32x4 acc = {0.0f, 0.0f, 0.0f, 0.0f};
#pragma unroll
      for (int kbl = 0; kbl < 8; ++kbl) {
        const unsigned byt = bytes[rbase + kbl * 4];
        const uint2 lo2 = lut[byt & 15u];
        const uint2 hi2 = lut[byt >> 4];
        const u32x4 A = {lo2.x, lo2.y, hi2.x, hi2.y};
        const short8 af = __builtin_bit_cast(short8, A);
        acc = __builtin_amdgcn_mfma_f32_16x16x32_bf16(
            af, __builtin_bit_cast(short8, bhi[kbl]), acc, 0, 0, 0);
      }
      if (n15 < NO_)
        *reinterpret_cast<f32x4*>(
            &comb[w * 640 + b * 160 + g * 40 + n15 * 4]) = acc;
    }
    __syncthreads();

    if (w < 4 && lane < NO_) {
      const float* cbase = comb + w * 160 + lane * 4;
#pragma unroll
      for (int tl = 0; tl < SO_TC; ++tl) {
        const int off = (tl >> 2) * 40 + (tl & 3);
        float s = 0.0f;
#pragma unroll
        for (int kk = 0; kk < 8; ++kk) s += cbase[kk * 640 + off];
        const float cur2 = s + b2v;
        float m = fmaf(0.95f, mem2, cur2);
        m = m - spk2;
        mem2 = m;
        spk2 = (m > 1.0f) ? 1.0f : 0.0f;
        const int t = ch * SO_TC + tl;
        srec[(size_t)t * (B_ * NO_)] = spk2;
        mrec[(size_t)t * (B_ * NO_)] = m;
      }
    }
  }
}

// ---------------------------------------------------------------------------
#define CUR1_BYTES ((size_t)B_ * NH_ * 4)            // 16 MB
// xc/w1c (12 MB each) alias the bits region: gemm reads them before spikegen
// overwrites with bits (stream-ordered).

extern "C" void kernel_launch(void* const* d_in, const int* in_sizes, int n_in,
                              void* d_out, int out_size, void* d_ws, size_t ws_size,
                              hipStream_t stream) {
  const float* x  = (const float*)d_in[0];
  const float* w1 = (const float*)d_in[1];
  const float* b1 = (const float*)d_in[2];
  const float* w2 = (const float*)d_in[3];
  const float* b2 = (const float*)d_in[4];
  float* out = (float*)d_out;
  float* cur1 = (float*)d_ws;
  unsigned short* xc  = (unsigned short*)((char*)d_ws + CUR1_BYTES);
  unsigned short* w1c = xc + (size_t)2048 * KP;
  unsigned* bitsg = (unsigned*)((char*)d_ws + CUR1_BYTES);

  float* spk2_rec = out;
  float* mem2_rec = out + (size_t)T_ * B_ * NO_;

  convert_hl<<<4096, 256, 0, stream>>>(x, w1, xc, w1c);
  dim3 g1(NH_ / 128, B_ / 64);
  gemm_cur1<<<g1, 512, 0, stream>>>(xc, w1c, b1, cur1);
  spikegen<<<B_ / 2, 512, 0, stream>>>(cur1, (unsigned char*)bitsg);
  snn_out<<<B_ / 4, 512, 0, stream>>>(bitsg, w2, b2, spk2_rec, mem2_rec);
}

// Round 33
// 161.833 us; speedup vs baseline: 1.0073x; 1.0073x over previous
//
#include <hip/hip_runtime.h>
#include <hip/hip_bf16.h>

// SNN: B=2048, NI=1024, NH=2048, NO=10, T=128, BETA=0.95, THR=1.0
// r33 = r32 + spikegen 60KB dummy LDS. Across the session, every LDS=0
// kernel got a starved VGPR budget (20-24 at ~35 live -> AGPR parking,
// ~1.7x VALU bloat) while every large-LDS kernel got a sane one. 60KB
// forces the occupancy heuristic to the SAME 2 blocks/CU we already
// measure (48%), but raises the register budget to 128 -> the asm's 27
// live operands fit, no per-iteration parking. Single-variable change.

#define B_   2048
#define NI_  1024
#define NH_  2048
#define NO_  10
#define T_   128
#define KP   3072   // concatenated K'

typedef __attribute__((ext_vector_type(8))) short short8;
typedef __attribute__((ext_vector_type(4))) float f32x4;
typedef __attribute__((ext_vector_type(4))) unsigned int u32x4;

__device__ __forceinline__ unsigned int bf16_rne(float f) {
  unsigned int u = __float_as_uint(f);
  return (u + 0x7FFFu + ((u >> 16) & 1u)) >> 16;
}

// ---------------- Kernel 0: convert x,w1 -> bf16 segment rows (K'=3072) -----
// xc row  = [xh(0..1023) | xh | xl];  w1c row = [wh | wl | wh].
__global__ __launch_bounds__(256) void convert_hl(
    const float* __restrict__ x, const float* __restrict__ w1,
    unsigned short* __restrict__ xc, unsigned short* __restrict__ w1c) {
  const int gidx = blockIdx.x * 256 + threadIdx.x;   // 0..2^20-1
  const int mat = gidx >> 19;
  const int loc = gidx & 524287;
  const int row = loc >> 8;
  const int kq = loc & 255;                          // float4 index in row

  const float* src = (mat ? w1 : x) + (size_t)row * NI_ + kq * 4;
  unsigned short* dst = (mat ? w1c : xc) + (size_t)row * KP + kq * 4;
  const int hi2_off = mat ? 2048 : 1024;  // second hi segment
  const int lo_off  = mat ? 1024 : 2048;  // lo segment

  const float4 v = *reinterpret_cast<const float4*>(src);
  const float f[4] = {v.x, v.y, v.z, v.w};
  unsigned h[4], l[4];
#pragma unroll
  for (int c = 0; c < 4; ++c) {
    h[c] = bf16_rne(f[c]);
    l[c] = bf16_rne(f[c] - __uint_as_float(h[c] << 16));
  }
  const uint2 hw = uint2{h[0] | (h[1] << 16), h[2] | (h[3] << 16)};
  const uint2 lw = uint2{l[0] | (l[1] << 16), l[2] | (l[3] << 16)};
  *reinterpret_cast<uint2*>(dst) = hw;
  *reinterpret_cast<uint2*>(dst + hi2_off) = hw;
  *reinterpret_cast<uint2*>(dst + lo_off) = lw;
}

// ---------------- Kernel 1: cur1 = xc @ w1c^T + b1 (bf16 GEMM, K'=3072) -----
#define RS 144
#define GA_OFF 0
#define GB_OFF (64 * RS)             // 9216
#define G2_SMEM (GB_OFF + 128 * RS)  // 27648

__global__ __launch_bounds__(512, 2) void gemm_cur1(
    const unsigned short* __restrict__ xc,
    const unsigned short* __restrict__ w1c,
    const float* __restrict__ b1, float* __restrict__ cur1) {
  __shared__ __align__(16) char smem[G2_SMEM];
  const int tid = threadIdx.x;
  const int lane = tid & 63;
  const int wv = tid >> 6;
  const int wm = wv >> 2;
  const int wn = wv & 3;
  const int n15 = lane & 15;
  const int g = lane >> 4;
  const int brow = blockIdx.y * 64;
  const int bcol = blockIdx.x * 128;

  const int s_row = tid >> 3;
  const int s_o16 = tid & 7;

  f32x4 acc[2][2];
#pragma unroll
  for (int tm = 0; tm < 2; ++tm)
#pragma unroll
    for (int tn = 0; tn < 2; ++tn) acc[tm][tn] = f32x4{0, 0, 0, 0};

  for (int kt = 0; kt < KP; kt += 64) {
    {
      const uint4 v = *reinterpret_cast<const uint4*>(
          xc + (size_t)(brow + s_row) * KP + kt + s_o16 * 8);
      *reinterpret_cast<uint4*>(smem + GA_OFF + s_row * RS + s_o16 * 16) = v;
    }
#pragma unroll
    for (int p = 0; p < 2; ++p) {
      const int s = tid + p * 512;
      const int row = s >> 3, o16 = s & 7;
      const uint4 v = *reinterpret_cast<const uint4*>(
          w1c + (size_t)(bcol + row) * KP + kt + o16 * 8);
      *reinterpret_cast<uint4*>(smem + GB_OFF + row * RS + o16 * 16) = v;
    }
    __syncthreads();

#pragma unroll
    for (int kk = 0; kk < 2; ++kk) {
      short8 af[2], bf[2];
#pragma unroll
      for (int tm = 0; tm < 2; ++tm)
        af[tm] = *reinterpret_cast<const short8*>(
            smem + GA_OFF + (wm * 32 + tm * 16 + n15) * RS + kk * 64 + g * 16);
#pragma unroll
      for (int tn = 0; tn < 2; ++tn)
        bf[tn] = *reinterpret_cast<const short8*>(
            smem + GB_OFF + (wn * 32 + tn * 16 + n15) * RS + kk * 64 + g * 16);
#pragma unroll
      for (int tm = 0; tm < 2; ++tm)
#pragma unroll
        for (int tn = 0; tn < 2; ++tn)
          acc[tm][tn] = __builtin_amdgcn_mfma_f32_16x16x32_bf16(
              af[tm], bf[tn], acc[tm][tn], 0, 0, 0);
    }
    __syncthreads();
  }

#pragma unroll
  for (int tn = 0; tn < 2; ++tn) {
    const int col = bcol + wn * 32 + tn * 16 + n15;
    const float bias = b1[col];
#pragma unroll
    for (int tm = 0; tm < 2; ++tm) {
      const int rowb = brow + wm * 32 + tm * 16 + g * 4;
#pragma unroll
      for (int r = 0; r < 4; ++r)
        cur1[(size_t)(rowb + r) * NH_ + col] = acc[tm][tn][r] + bias;
    }
  }
}

// ---------------- Kernel A: spikegen — asm LIF + 60KB LDS budget pad --------
// 512 threads = 8 waves = 2 batches (bq=w>>2, qf=w&3); 8 neurons/lane.
// Byte b = qf*64+lane of the (b,t) 256-byte row covers neurons 8b..8b+7.
// Per neuron-step: fma, cmp, cndmask-s, sub-cc, addc = 5 inst; one block.
__global__ __launch_bounds__(512) void spikegen(
    const float* __restrict__ cur1, unsigned char* __restrict__ bits8) {
  // 60KB pad -> heuristic capped at 2 blocks/CU (= measured occupancy
  // anyway) -> VGPR budget 128 -> no AGPR parking around the asm.
  __shared__ char pad[60 * 1024];
  asm volatile("" ::"v"((unsigned)(size_t)pad));  // escape: keep allocation

  const int lane = threadIdx.x & 63;
  const int w = threadIdx.x >> 6;
  const int bq = w >> 2;
  const int qf = w & 3;
  const int bb = blockIdx.x * 2 + bq;

  float m0, m1, m2, m3, m4, m5, m6, m7;
  float v0, v1, v2, v3, v4, v5, v6, v7;   // c1
  float c0, c1_, c2, c3, c4, c5, c6, c7;  // cc carry
  {
    const float* base = cur1 + (size_t)bb * NH_ + qf * 512 + lane * 8;
    const float4 a = *reinterpret_cast<const float4*>(base);
    const float4 b = *reinterpret_cast<const float4*>(base + 4);
    v0 = a.x; v1 = a.y; v2 = a.z; v3 = a.w;
    v4 = b.x; v5 = b.y; v6 = b.z; v7 = b.w;
    c0 = v0; c1_ = v1; c2 = v2; c3 = v3;
    c4 = v4; c5 = v5; c6 = v6; c7 = v7;
    m0 = m1 = m2 = m3 = m4 = m5 = m6 = m7 = 0.0f;
  }

  float fone = 1.0f;
  unsigned char* dst = bits8 + (size_t)bb * T_ * 256 + qf * 64 + lane;

  for (int t = 0; t < T_; ++t) {
    unsigned W = 0;
    float st;
    asm volatile(
        "v_fma_f32 %[m7], %[k], %[m7], %[c7]\n\t"
        "v_cmp_lt_f32 vcc, 1.0, %[m7]\n\t"
        "v_cndmask_b32 %[s], 0, %[one], vcc\n\t"
        "v_sub_f32 %[c7], %[v7], %[s]\n\t"
        "v_addc_co_u32 %[wr], vcc, %[wr], %[wr], vcc\n\t"
        "v_fma_f32 %[m6], %[k], %[m6], %[c6]\n\t"
        "v_cmp_lt_f32 vcc, 1.0, %[m6]\n\t"
        "v_cndmask_b32 %[s], 0, %[one], vcc\n\t"
        "v_sub_f32 %[c6], %[v6], %[s]\n\t"
        "v_addc_co_u32 %[wr], vcc, %[wr], %[wr], vcc\n\t"
        "v_fma_f32 %[m5], %[k], %[m5], %[c5]\n\t"
        "v_cmp_lt_f32 vcc, 1.0, %[m5]\n\t"
        "v_cndmask_b32 %[s], 0, %[one], vcc\n\t"
        "v_sub_f32 %[c5], %[v5], %[s]\n\t"
        "v_addc_co_u32 %[wr], vcc, %[wr], %[wr], vcc\n\t"
        "v_fma_f32 %[m4], %[k], %[m4], %[c4]\n\t"
        "v_cmp_lt_f32 vcc, 1.0, %[m4]\n\t"
        "v_cndmask_b32 %[s], 0, %[one], vcc\n\t"
        "v_sub_f32 %[c4], %[v4], %[s]\n\t"
        "v_addc_co_u32 %[wr], vcc, %[wr], %[wr], vcc\n\t"
        "v_fma_f32 %[m3], %[k], %[m3], %[c3]\n\t"
        "v_cmp_lt_f32 vcc, 1.0, %[m3]\n\t"
        "v_cndmask_b32 %[s], 0, %[one], vcc\n\t"
        "v_sub_f32 %[c3], %[v3], %[s]\n\t"
        "v_addc_co_u32 %[wr], vcc, %[wr], %[wr], vcc\n\t"
        "v_fma_f32 %[m2], %[k], %[m2], %[c2]\n\t"
        "v_cmp_lt_f32 vcc, 1.0, %[m2]\n\t"
        "v_cndmask_b32 %[s], 0, %[one], vcc\n\t"
        "v_sub_f32 %[c2], %[v2], %[s]\n\t"
        "v_addc_co_u32 %[wr], vcc, %[wr], %[wr], vcc\n\t"
        "v_fma_f32 %[m1], %[k], %[m1], %[c1]\n\t"
        "v_cmp_lt_f32 vcc, 1.0, %[m1]\n\t"
        "v_cndmask_b32 %[s], 0, %[one], vcc\n\t"
        "v_sub_f32 %[c1], %[v1], %[s]\n\t"
        "v_addc_co_u32 %[wr], vcc, %[wr], %[wr], vcc\n\t"
        "v_fma_f32 %[m0], %[k], %[m0], %[c0]\n\t"
        "v_cmp_lt_f32 vcc, 1.0, %[m0]\n\t"
        "v_cndmask_b32 %[s], 0, %[one], vcc\n\t"
        "v_sub_f32 %[c0], %[v0], %[s]\n\t"
        "v_addc_co_u32 %[wr], vcc, %[wr], %[wr], vcc\n\t"
        : [wr] "+v"(W), [s] "=&v"(st),
          [m7] "+v"(m7), [m6] "+v"(m6), [m5] "+v"(m5), [m4] "+v"(m4),
          [m3] "+v"(m3), [m2] "+v"(m2), [m1] "+v"(m1), [m0] "+v"(m0),
          [c7] "+v"(c7), [c6] "+v"(c6), [c5] "+v"(c5), [c4] "+v"(c4),
          [c3] "+v"(c3), [c2] "+v"(c2), [c1] "+v"(c1_), [c0] "+v"(c0)
        : [k] "s"(0.95f), [one] "v"(fone),
          [v7] "v"(v7), [v6] "v"(v6), [v5] "v"(v5), [v4] "v"(v4),
          [v3] "v"(v3), [v2] "v"(v2), [v1] "v"(v1), [v0] "v"(v0)
        : "vcc");

    dst[t * 256] = (unsigned char)W;
  }
}

// ---------------- Kernel B: snn_out (r20 frozen) ----------------------------
#define SO_TC 16

__global__ __launch_bounds__(512, 2) void snn_out(
    const unsigned* __restrict__ bitsg, const float* __restrict__ w2,
    const float* __restrict__ b2, float* __restrict__ spk2_rec,
    float* __restrict__ mem2_rec) {
  __shared__ uint2 lut[16];
  __shared__ __align__(16) unsigned bitsl[64 * 68];
  __shared__ __align__(16) float comb[8 * 640];
  const int tid = threadIdx.x;
  const int lane = tid & 63;
  const int w = tid >> 6;
  const int bbase = blockIdx.x * 4;

  if (tid < 16) {
    lut[tid] = uint2{(tid & 1 ? 0x3F80u : 0u) | (tid & 2 ? 0x3F800000u : 0u),
                     (tid & 4 ? 0x3F80u : 0u) | (tid & 8 ? 0x3F800000u : 0u)};
  }

  u32x4 bhi[8];
  {
    const int o = lane & 15;
    const int koff = (lane >> 4) * 8;
#pragma unroll
    for (int kbl = 0; kbl < 8; ++kbl) {
      const int kb = w * 8 + kbl;
      unsigned int hw[4];
#pragma unroll
      for (int p = 0; p < 4; ++p) {
        unsigned int h0 = 0, h1 = 0;
        if (o < NO_) {
          const int k = kb * 32 + koff + p * 2;
          h0 = bf16_rne(w2[(size_t)o * NH_ + k]);
          h1 = bf16_rne(w2[(size_t)o * NH_ + k + 1]);
        }
        hw[p] = h0 | (h1 << 16);
      }
      bhi[kbl] = u32x4{hw[0], hw[1], hw[2], hw[3]};
    }
  }

  float mem2 = 0.0f, spk2 = 0.0f, b2v = 0.0f;
  float *srec = nullptr, *mrec = nullptr;
  if (w < 4 && lane < NO_) {
    b2v = b2[lane];
    srec = spk2_rec + (size_t)(bbase + w) * NO_ + lane;
    mrec = mem2_rec + (size_t)(bbase + w) * NO_ + lane;
  }

  const int n15 = lane & 15;
  const int g = lane >> 4;
  const unsigned char* bytes = reinterpret_cast<const unsigned char*>(bitsl);

  for (int ch = 0; ch < T_ / SO_TC; ++ch) {
#pragma unroll
    for (int j = 0; j < 2; ++j) {
      const int q = tid + j * 512;
      const int row = q >> 4;
      const int kq = q & 15;
      const int b = row >> 4, tl = row & 15;
      const uint4 v = *reinterpret_cast<const uint4*>(
          bitsg + ((size_t)(bbase + b) * T_ + ch * SO_TC + tl) * 64 + kq * 4);
      *reinterpret_cast<uint4*>(bitsl + row * 68 + kq * 4) = v;
    }
    __syncthreads();

#pragma unroll
    for (int b = 0; b < 4; ++b) {
      const int rbase = ((b * SO_TC + n15) * 68 + w * 8) * 4 + g;
      f32x4 acc = {0.0f, 0.0f, 0.0f, 0.0f};
#pragma unroll
      for (int kbl = 0; kbl < 8; ++kbl) {
        const unsigned byt = bytes[rbase + kbl * 4];
        const uint2 lo2 = lut[byt & 15u];
        const uint2 hi2 = lut[byt >> 4];
        const u32x4 A = {lo2.x, lo2.y, hi2.x, hi2.y};
        const short8 af = __builtin_bit_cast(short8, A);
        acc = __builtin_amdgcn_mfma_f32_16x16x32_bf16(
            af, __builtin_bit_cast(short8, bhi[kbl]), acc, 0, 0, 0);
      }
      if (n15 < NO_)
        *reinterpret_cast<f32x4*>(
            &comb[w * 640 + b * 160 + g * 40 + n15 * 4]) = acc;
    }
    __syncthreads();

    if (w < 4 && lane < NO_) {
      const float* cbase = comb + w * 160 + lane * 4;
#pragma unroll
      for (int tl = 0; tl < SO_TC; ++tl) {
        const int off = (tl >> 2) * 40 + (tl & 3);
        float s = 0.0f;
#pragma unroll
        for (int kk = 0; kk < 8; ++kk) s += cbase[kk * 640 + off];
        const float cur2 = s + b2v;
        float m = fmaf(0.95f, mem2, cur2);
        m = m - spk2;
        mem2 = m;
        spk2 = (m > 1.0f) ? 1.0f : 0.0f;
        const int t = ch * SO_TC + tl;
        srec[(size_t)t * (B_ * NO_)] = spk2;
        mrec[(size_t)t * (B_ * NO_)] = m;
      }
    }
  }
}

// ---------------------------------------------------------------------------
#define CUR1_BYTES ((size_t)B_ * NH_ * 4)            // 16 MB
// xc/w1c (12 MB each) alias the bits region: gemm reads them before spikegen
// overwrites with bits (stream-ordered).

extern "C" void kernel_launch(void* const* d_in, const int* in_sizes, int n_in,
                              void* d_out, int out_size, void* d_ws, size_t ws_size,
                              hipStream_t stream) {
  const float* x  = (const float*)d_in[0];
  const float* w1 = (const float*)d_in[1];
  const float* b1 = (const float*)d_in[2];
  const float* w2 = (const float*)d_in[3];
  const float* b2 = (const float*)d_in[4];
  float* out = (float*)d_out;
  float* cur1 = (float*)d_ws;
  unsigned short* xc  = (unsigned short*)((char*)d_ws + CUR1_BYTES);
  unsigned short* w1c = xc + (size_t)2048 * KP;
  unsigned* bitsg = (unsigned*)((char*)d_ws + CUR1_BYTES);

  float* spk2_rec = out;
  float* mem2_rec = out + (size_t)T_ * B_ * NO_;

  convert_hl<<<4096, 256, 0, stream>>>(x, w1, xc, w1c);
  dim3 g1(NH_ / 128, B_ / 64);
  gemm_cur1<<<g1, 512, 0, stream>>>(xc, w1c, b1, cur1);
  spikegen<<<B_ / 2, 512, 0, stream>>>(cur1, (unsigned char*)bitsg);
  snn_out<<<B_ / 4, 512, 0, stream>>>(bitsg, w2, b2, spk2_rec, mem2_rec);
}